// Round 4
// baseline (327.146 us; speedup 1.0000x reference)
//
#include <hip/hip_runtime.h>
#include <hip/hip_bf16.h>
#include <math.h>

// ---------------- problem constants ----------------
#define N_ROWS 65536
#define H 256
#define DOUT 64
#define NC 4
#define NLAYERS_HIDDEN 3
#define DIN_PE 84
#define KPE 96          // padded K for layer 0 (84 -> 96, zeros)
#define XE_STRIDE 104   // padded LDS row stride for xe
#define BM 128          // rows per block
#define FB_STRIDE 68    // fp32 out-staging row stride (pad for banks, 16B align)

// fragment-ordered weight chunk: one (kb, nblk) pair = 64 lanes x 8 bf16 = 512
#define CHUNK 512
#define WT0_PER_E (3 * 16 * CHUNK)      // 24576
#define WTH_PER_L (8 * 16 * CHUNK)      // 65536
#define WTOUT_PER_E (8 * 4 * CHUNK)     // 16384

using bf16 = __hip_bfloat16;
typedef __bf16 bf16x8 __attribute__((ext_vector_type(8)));
typedef float f32x4 __attribute__((ext_vector_type(4)));

// ---------------- bucket rows by expert ----------------
__global__ void bucket_kernel(const int* __restrict__ layer_id,
                              int* __restrict__ gcnt, int* __restrict__ idx) {
  __shared__ int lcnt[NC];
  __shared__ int lbase[NC];
  const int tid = threadIdx.x;
  if (tid < NC) lcnt[tid] = 0;
  __syncthreads();
  const int i = blockIdx.x * blockDim.x + tid;
  const int e = layer_id[i];
  const int lp = atomicAdd(&lcnt[e], 1);
  __syncthreads();
  if (tid < NC) lbase[tid] = atomicAdd(&gcnt[tid], lcnt[tid]);
  __syncthreads();
  idx[e * N_ROWS + lbase[e] + lp] = i;
}

// ---------------- fp32 -> bf16 fragment-ordered weights ----------------
// Layout per (kb-step, nblk) chunk of 512 bf16: element [lane*8 + j] holds
// W^T[n][k] with n = nblk*16 + (lane&15), k = kb*32 + (lane>>4)*8 + j.
// So the MFMA B-fragment load is ONE coalesced 1KB load: base + lane*16B.
__global__ void prep_weights(const float* __restrict__ W0,
                             const float* __restrict__ Wh,
                             const float* __restrict__ Wout,
                             bf16* __restrict__ wt0, bf16* __restrict__ wth,
                             bf16* __restrict__ wtout) {
  const int n0 = NC * WT0_PER_E;
  const int nh = NC * 3 * WTH_PER_L;
  const int no = NC * WTOUT_PER_E;
  const int total = n0 + nh + no;
  for (int i = blockIdx.x * blockDim.x + threadIdx.x; i < total;
       i += gridDim.x * blockDim.x) {
    if (i < n0) {
      int c = i / WT0_PER_E; int r = i % WT0_PER_E;
      int kbi = r / (16 * CHUNK); int r2 = r % (16 * CHUNK);
      int nblk = r2 / CHUNK; int w = r2 % CHUNK;
      int lane = w / 8, j = w % 8;
      int n = nblk * 16 + (lane & 15);
      int k = kbi * 32 + (lane >> 4) * 8 + j;
      float v = (k < DIN_PE) ? W0[(c * DIN_PE + k) * H + n] : 0.f;
      wt0[i] = __float2bfloat16(v);
    } else if (i < n0 + nh) {
      int u = i - n0;
      int cl = u / WTH_PER_L; int r = u % WTH_PER_L;   // cl = c*3 + l
      int kbi = r / (16 * CHUNK); int r2 = r % (16 * CHUNK);
      int nblk = r2 / CHUNK; int w = r2 % CHUNK;
      int lane = w / 8, j = w % 8;
      int n = nblk * 16 + (lane & 15);
      int k = kbi * 32 + (lane >> 4) * 8 + j;
      wth[u] = __float2bfloat16(Wh[(cl * H + k) * H + n]);
    } else {
      int u = i - n0 - nh;
      int c = u / WTOUT_PER_E; int r = u % WTOUT_PER_E;
      int kbi = r / (4 * CHUNK); int r2 = r % (4 * CHUNK);
      int nblk = r2 / CHUNK; int w = r2 % CHUNK;
      int lane = w / 8, j = w % 8;
      int n = nblk * 16 + (lane & 15);
      int k = kbi * 32 + (lane >> 4) * 8 + j;
      wtout[u] = __float2bfloat16(Wout[(c * H + k) * DOUT + n]);
    }
  }
}

// ---------------- main fused MLP ----------------
// grid: (N_ROWS/BM, NC); block: 256 (4 waves). Wave w owns cols [64w,64w+64)
// of the 128xH intermediate (8 m-tiles x 4 n-tiles). 32 MFMAs per 4 B-loads
// per K-step -> 2x the MFMA duty of BM=64.
__global__ __launch_bounds__(256, 2) void mlp_kernel(
    const float* __restrict__ x, const float* __restrict__ in_dim,
    const int* __restrict__ gcnt, const int* __restrict__ idx,
    const bf16* __restrict__ wt0, const float* __restrict__ b0,
    const bf16* __restrict__ wth, const float* __restrict__ bh,
    const float* __restrict__ scal, const bf16* __restrict__ wtout,
    const float* __restrict__ bout, float* __restrict__ out) {
  const int e = blockIdx.y;
  const int cnt = gcnt[e];
  const int base = blockIdx.x * BM;
  if (base >= cnt) return;

  __shared__ int ridx[BM];
  __shared__ float indim_s[BM];
  // overlays: xe [128][104] bf16 (26624B) -> hbuf [128][256] bf16 swizzled
  // (65536B) -> fbuf [128][68] f32 (34816B). Barrier-protected transitions.
  __shared__ __align__(16) char smem[BM * H * 2];
  bf16* xe = (bf16*)smem;
  bf16* hbuf = (bf16*)smem;
  float* fbuf = (float*)smem;

  const int tid = threadIdx.x;
  if (tid < BM) {
    int p = base + tid;
    int ri = (p < cnt) ? idx[e * N_ROWS + p] : -1;
    ridx[tid] = ri;
    indim_s[tid] = (ri >= 0) ? in_dim[ri] : 1.f;
  }
  __syncthreads();

  // ---- positional encoding: 4 threads per row (2 passes of 64 rows) ----
#pragma unroll
  for (int p = 0; p < 2; ++p) {
    const int r = (tid >> 2) + p * 64, d = tid & 3;
    const int ri = ridx[r];
    float xd = 0.f, x3 = 1.f;
    if (ri >= 0) { xd = x[ri * 4 + d]; x3 = x[ri * 4 + 3]; }
    float v = (d < 3) ? (xd / x3) : x3;
    if (ri < 0) v = 0.f;
    bf16* row = xe + r * XE_STRIDE;
    row[d] = __float2bfloat16(v);
    float f = 3.14159265358979323846f;
#pragma unroll
    for (int q = 0; q < 10; ++q) {
      float sn, cs;
      __sincosf(v * f, &sn, &cs);
      row[4 + q * 8 + d * 2] = __float2bfloat16(sn);
      row[4 + q * 8 + d * 2 + 1] = __float2bfloat16(cs);
      f *= 2.f;
    }
#pragma unroll
    for (int c = DIN_PE + d; c < XE_STRIDE; c += 4) row[c] = __float2bfloat16(0.f);
  }
  __syncthreads();

  const int lane = tid & 63;
  const int wid = tid >> 6;
  const int l15 = lane & 15;
  const int lq = lane >> 4;
  const int wb = wid * 64;  // this wave's column base

  f32x4 acc[8][4];

  // ---- layer 0: xe[128xKPE] @ wt0^T -> h ----
  {
    const bf16* W = wt0 + (size_t)e * WT0_PER_E + lane * 8;
    const float* bias = b0 + e * H;
#pragma unroll
    for (int nt = 0; nt < 4; ++nt) {
      float b = bias[wb + nt * 16 + l15];
      f32x4 bv = {b, b, b, b};
#pragma unroll
      for (int mt = 0; mt < 8; ++mt) acc[mt][nt] = bv;
    }
#pragma unroll
    for (int kb = 0; kb < KPE; kb += 32) {
      bf16x8 a[8], bw[4];
#pragma unroll
      for (int nt = 0; nt < 4; ++nt)
        bw[nt] = *(const bf16x8*)(W + ((kb >> 5) * 16 + wid * 4 + nt) * CHUNK);
#pragma unroll
      for (int mt = 0; mt < 8; ++mt) {
        int row = mt * 16 + l15;
        a[mt] = *(const bf16x8*)(xe + row * XE_STRIDE + kb + lq * 8);
      }
#pragma unroll
      for (int mt = 0; mt < 8; ++mt)
#pragma unroll
        for (int nt = 0; nt < 4; ++nt)
          acc[mt][nt] = __builtin_amdgcn_mfma_f32_16x16x32_bf16(
              a[mt], bw[nt], acc[mt][nt], 0, 0, 0);
    }
    __syncthreads();  // all waves done reading xe before hbuf overwrites it
    // epilogue: relu -> swizzled LDS write (no residual at layer 0)
#pragma unroll
    for (int mt = 0; mt < 8; ++mt)
#pragma unroll
      for (int nt = 0; nt < 4; ++nt) {
        int col = wb + nt * 16 + l15;
#pragma unroll
        for (int j = 0; j < 4; ++j) {
          int row = mt * 16 + lq * 4 + j;
          float hv = fmaxf(acc[mt][nt][j], 0.f);
          int byte = (row * H + col) * 2;
          byte ^= ((row & 7) << 4);
          *(bf16*)((char*)hbuf + byte) = __float2bfloat16(hv);
        }
      }
  }
  __syncthreads();

  // ---- hidden residual layers ----
#pragma unroll
  for (int l = 0; l < NLAYERS_HIDDEN; ++l) {
    const bf16* W = wth + (size_t)(e * 3 + l) * WTH_PER_L + lane * 8;
    const float* bias = bh + (e * 3 + l) * H;
    const float sc = scal[e * 3 + l];
#pragma unroll
    for (int nt = 0; nt < 4; ++nt) {
      float b = bias[wb + nt * 16 + l15];
      f32x4 bv = {b, b, b, b};
#pragma unroll
      for (int mt = 0; mt < 8; ++mt) acc[mt][nt] = bv;
    }
#pragma unroll
    for (int kb = 0; kb < H; kb += 32) {
      bf16x8 a[8], bw[4];
#pragma unroll
      for (int nt = 0; nt < 4; ++nt)
        bw[nt] = *(const bf16x8*)(W + ((kb >> 5) * 16 + wid * 4 + nt) * CHUNK);
#pragma unroll
      for (int mt = 0; mt < 8; ++mt) {
        int row = mt * 16 + l15;
        int byte = (row * H + kb + lq * 8) * 2;
        byte ^= ((row & 7) << 4);
        a[mt] = *(const bf16x8*)((const char*)hbuf + byte);
      }
#pragma unroll
      for (int mt = 0; mt < 8; ++mt)
#pragma unroll
        for (int nt = 0; nt < 4; ++nt)
          acc[mt][nt] = __builtin_amdgcn_mfma_f32_16x16x32_bf16(
              a[mt], bw[nt], acc[mt][nt], 0, 0, 0);
    }
    __syncthreads();  // all waves done READING hbuf before overwrite
#pragma unroll
    for (int mt = 0; mt < 8; ++mt)
#pragma unroll
      for (int nt = 0; nt < 4; ++nt) {
        int col = wb + nt * 16 + l15;
#pragma unroll
        for (int j = 0; j < 4; ++j) {
          int row = mt * 16 + lq * 4 + j;
          int byte = (row * H + col) * 2;
          byte ^= ((row & 7) << 4);
          bf16* p = (bf16*)((char*)hbuf + byte);
          float hp = __bfloat162float(*p);  // residual: same-thread RMW
          float hv = sc * fmaxf(acc[mt][nt][j], 0.f) + hp;
          *p = __float2bfloat16(hv);
        }
      }
    __syncthreads();
  }

  // ---- output layer: h[128xH] @ wtout^T -> fbuf[128x64] fp32 ----
  {
    const bf16* W = wtout + (size_t)e * WTOUT_PER_E + lane * 8;
    const float* bias = bout + e * DOUT;
    f32x4 facc[2][4];
#pragma unroll
    for (int nt = 0; nt < 4; ++nt) {
      float b = bias[nt * 16 + l15];
      f32x4 bv = {b, b, b, b};
#pragma unroll
      for (int om = 0; om < 2; ++om) facc[om][nt] = bv;
    }
#pragma unroll
    for (int kb = 0; kb < H; kb += 32) {
      bf16x8 a[2], bw[4];
#pragma unroll
      for (int nt = 0; nt < 4; ++nt)
        bw[nt] = *(const bf16x8*)(W + ((kb >> 5) * 4 + nt) * CHUNK);
#pragma unroll
      for (int om = 0; om < 2; ++om) {
        int arow = wid * 32 + om * 16 + l15;  // wave w owns rows [32w,32w+32)
        int byte = (arow * H + kb + lq * 8) * 2;
        byte ^= ((arow & 7) << 4);
        a[om] = *(const bf16x8*)((const char*)hbuf + byte);
      }
#pragma unroll
      for (int om = 0; om < 2; ++om)
#pragma unroll
        for (int nt = 0; nt < 4; ++nt)
          facc[om][nt] = __builtin_amdgcn_mfma_f32_16x16x32_bf16(
              a[om], bw[nt], facc[om][nt], 0, 0, 0);
    }
    __syncthreads();  // hbuf dead; fbuf overlays it
#pragma unroll
    for (int om = 0; om < 2; ++om)
#pragma unroll
      for (int nt = 0; nt < 4; ++nt) {
        int col = nt * 16 + l15;
#pragma unroll
        for (int j = 0; j < 4; ++j) {
          int row = wid * 32 + om * 16 + lq * 4 + j;
          fbuf[row * FB_STRIDE + col] = facc[om][nt][j];
        }
      }
  }
  __syncthreads();

  // ---- coalesced scatter: full 256B rows via float4 lanes ----
#pragma unroll
  for (int p = 0; p < 8; ++p) {
    int item = p * 256 + tid;
    int row = item >> 4;
    int ch = item & 15;
    int ri = ridx[row];
    if (ri >= 0) {
      f32x4 v = *(const f32x4*)(fbuf + row * FB_STRIDE + ch * 4);
      float inv = indim_s[row];
      v[0] /= inv; v[1] /= inv; v[2] /= inv; v[3] /= inv;
      *(f32x4*)(out + (size_t)ri * DOUT + ch * 4) = v;
    }
  }
}

// ---------------- launch ----------------
extern "C" void kernel_launch(void* const* d_in, const int* in_sizes, int n_in,
                              void* d_out, int out_size, void* d_ws,
                              size_t ws_size, hipStream_t stream) {
  const float* x = (const float*)d_in[0];
  const float* in_dim = (const float*)d_in[1];
  const int* layer_id = (const int*)d_in[2];
  const float* W0 = (const float*)d_in[3];
  const float* b0 = (const float*)d_in[4];
  const float* Wh = (const float*)d_in[5];
  const float* bh = (const float*)d_in[6];
  const float* scal = (const float*)d_in[7];
  const float* Wout = (const float*)d_in[8];
  const float* bout = (const float*)d_in[9];
  float* out = (float*)d_out;

  char* ws = (char*)d_ws;
  int* gcnt = (int*)ws;                                  // 16 B
  int* idx = (int*)(ws + 16);                            // NC*N_ROWS*4 = 1 MB
  bf16* wt0 = (bf16*)(ws + 16 + (size_t)NC * N_ROWS * 4);
  bf16* wth = wt0 + NC * WT0_PER_E;
  bf16* wtout = wth + NC * 3 * WTH_PER_L;

  hipMemsetAsync(gcnt, 0, NC * sizeof(int), stream);
  bucket_kernel<<<N_ROWS / 256, 256, 0, stream>>>(layer_id, gcnt, idx);
  prep_weights<<<512, 256, 0, stream>>>(W0, Wh, Wout, wt0, wth, wtout);
  mlp_kernel<<<dim3(N_ROWS / BM, NC), 256, 0, stream>>>(
      x, in_dim, gcnt, idx, wt0, b0, wth, bh, scal, wtout, bout, out);
}

// Round 5
// 150.544 us; speedup vs baseline: 2.1731x; 2.1731x over previous
//
#include <hip/hip_runtime.h>
#include <hip/hip_bf16.h>
#include <math.h>

// ---------------- problem constants ----------------
#define N_ROWS 65536
#define H 256
#define DOUT 64
#define NC 4
#define NLAYERS_HIDDEN 3
#define DIN_PE 84
#define KPE 96          // padded K for layer 0 (84 -> 96, zeros)
#define XE_STRIDE 104   // padded LDS row stride for xe
#define BM 64           // rows per block
#define FB_STRIDE 68    // fp32 out-staging row stride

// fragment-ordered weight chunk: one (kstep, nblk) pair = 64 lanes x 8 bf16
#define CHUNK 512
#define WT0_PER_E (3 * 16 * CHUNK)      // 24576
#define WTH_PER_L (8 * 16 * CHUNK)      // 65536
#define WTOUT_PER_E (8 * 4 * CHUNK)     // 16384

using bf16 = __hip_bfloat16;
typedef __bf16 bf16x8 __attribute__((ext_vector_type(8)));
typedef float f32x4 __attribute__((ext_vector_type(4)));

// ---------------- bucket rows by expert ----------------
__global__ void bucket_kernel(const int* __restrict__ layer_id,
                              int* __restrict__ gcnt, int* __restrict__ idx) {
  __shared__ int lcnt[NC];
  __shared__ int lbase[NC];
  const int tid = threadIdx.x;
  if (tid < NC) lcnt[tid] = 0;
  __syncthreads();
  const int i = blockIdx.x * blockDim.x + tid;
  const int e = layer_id[i];
  const int lp = atomicAdd(&lcnt[e], 1);
  __syncthreads();
  if (tid < NC) lbase[tid] = atomicAdd(&gcnt[tid], lcnt[tid]);
  __syncthreads();
  idx[e * N_ROWS + lbase[e] + lp] = i;
}

// ---------------- fp32 -> bf16 fragment-ordered weights ----------------
// element [lane*8 + j] of chunk (kbi,nblk) holds W^T[n][k] with
// n = nblk*16 + (lane&15), k = kbi*32 + (lane>>4)*8 + j.
__global__ void prep_weights(const float* __restrict__ W0,
                             const float* __restrict__ Wh,
                             const float* __restrict__ Wout,
                             bf16* __restrict__ wt0, bf16* __restrict__ wth,
                             bf16* __restrict__ wtout) {
  const int n0 = NC * WT0_PER_E;
  const int nh = NC * 3 * WTH_PER_L;
  const int no = NC * WTOUT_PER_E;
  const int total = n0 + nh + no;
  for (int i = blockIdx.x * blockDim.x + threadIdx.x; i < total;
       i += gridDim.x * blockDim.x) {
    if (i < n0) {
      int c = i / WT0_PER_E; int r = i % WT0_PER_E;
      int kbi = r / (16 * CHUNK); int r2 = r % (16 * CHUNK);
      int nblk = r2 / CHUNK; int w = r2 % CHUNK;
      int lane = w / 8, j = w % 8;
      int n = nblk * 16 + (lane & 15);
      int k = kbi * 32 + (lane >> 4) * 8 + j;
      float v = (k < DIN_PE) ? W0[(c * DIN_PE + k) * H + n] : 0.f;
      wt0[i] = __float2bfloat16(v);
    } else if (i < n0 + nh) {
      int u = i - n0;
      int cl = u / WTH_PER_L; int r = u % WTH_PER_L;   // cl = c*3 + l
      int kbi = r / (16 * CHUNK); int r2 = r % (16 * CHUNK);
      int nblk = r2 / CHUNK; int w = r2 % CHUNK;
      int lane = w / 8, j = w % 8;
      int n = nblk * 16 + (lane & 15);
      int k = kbi * 32 + (lane >> 4) * 8 + j;
      wth[u] = __float2bfloat16(Wh[(cl * H + k) * H + n]);
    } else {
      int u = i - n0 - nh;
      int c = u / WTOUT_PER_E; int r = u % WTOUT_PER_E;
      int kbi = r / (4 * CHUNK); int r2 = r % (4 * CHUNK);
      int nblk = r2 / CHUNK; int w = r2 % CHUNK;
      int lane = w / 8, j = w % 8;
      int n = nblk * 16 + (lane & 15);
      int k = kbi * 32 + (lane >> 4) * 8 + j;
      wtout[u] = __float2bfloat16(Wout[(c * H + k) * DOUT + n]);
    }
  }
}

// ---------------- main fused MLP (rolled loops: small code footprint) ------
__global__ __launch_bounds__(256, 3) void mlp_kernel(
    const float* __restrict__ x, const float* __restrict__ in_dim,
    const int* __restrict__ gcnt, const int* __restrict__ idx,
    const bf16* __restrict__ wt0, const float* __restrict__ b0,
    const bf16* __restrict__ wth, const float* __restrict__ bh,
    const float* __restrict__ scal, const bf16* __restrict__ wtout,
    const float* __restrict__ bout, float* __restrict__ out) {
  const int e = blockIdx.y;
  const int cnt = gcnt[e];
  const int base = blockIdx.x * BM;
  if (base >= cnt) return;

  __shared__ int ridx[BM];
  __shared__ float indim_s[BM];
  // overlays: xe [64][104] bf16 (13312B) -> hbuf [64][256] bf16 swizzled
  // (32768B) -> fbuf [64][68] f32 (17408B). Barrier-protected transitions.
  __shared__ __align__(16) char smem[BM * H * 2];
  bf16* xe = (bf16*)smem;
  bf16* hbuf = (bf16*)smem;
  float* fbuf = (float*)smem;

  const int tid = threadIdx.x;
  if (tid < BM) {
    int p = base + tid;
    int ri = (p < cnt) ? idx[e * N_ROWS + p] : -1;
    ridx[tid] = ri;
    indim_s[tid] = (ri >= 0) ? in_dim[ri] : 1.f;
  }
  __syncthreads();

  // ---- positional encoding: 4 threads per row ----
  {
    const int r = tid >> 2, d = tid & 3;
    const int ri = ridx[r];
    float xd = 0.f, x3 = 1.f;
    if (ri >= 0) { xd = x[ri * 4 + d]; x3 = x[ri * 4 + 3]; }
    float v = (d < 3) ? (xd / x3) : x3;
    if (ri < 0) v = 0.f;
    bf16* row = xe + r * XE_STRIDE;
    row[d] = __float2bfloat16(v);
    float f = 3.14159265358979323846f;
#pragma unroll 1
    for (int q = 0; q < 10; ++q) {
      float sn, cs;
      __sincosf(v * f, &sn, &cs);
      row[4 + q * 8 + d * 2] = __float2bfloat16(sn);
      row[4 + q * 8 + d * 2 + 1] = __float2bfloat16(cs);
      f *= 2.f;
    }
#pragma unroll 1
    for (int c = DIN_PE + d; c < XE_STRIDE; c += 4) row[c] = __float2bfloat16(0.f);
  }
  __syncthreads();

  const int lane = tid & 63;
  const int wid = tid >> 6;
  const int l15 = lane & 15;
  const int lq = lane >> 4;
  const int wb = wid * 64;  // this wave's column base

  f32x4 acc[4][4];

  // ---- layer 0: xe[64xKPE] @ wt0^T -> h ----
  {
    const bf16* W = wt0 + (size_t)e * WT0_PER_E + lane * 8;
    const float* bias = b0 + e * H;
#pragma unroll
    for (int nt = 0; nt < 4; ++nt) {
      float b = bias[wb + nt * 16 + l15];
      f32x4 bv = {b, b, b, b};
#pragma unroll
      for (int mt = 0; mt < 4; ++mt) acc[mt][nt] = bv;
    }
#pragma unroll 1
    for (int kb = 0; kb < 3; ++kb) {  // kstep index (K = 3*32)
      bf16x8 a[4], bw[4];
#pragma unroll
      for (int nt = 0; nt < 4; ++nt)
        bw[nt] = *(const bf16x8*)(W + (kb * 16 + wid * 4 + nt) * CHUNK);
#pragma unroll
      for (int mt = 0; mt < 4; ++mt) {
        int row = mt * 16 + l15;
        a[mt] = *(const bf16x8*)(xe + row * XE_STRIDE + kb * 32 + lq * 8);
      }
#pragma unroll
      for (int mt = 0; mt < 4; ++mt)
#pragma unroll
        for (int nt = 0; nt < 4; ++nt)
          acc[mt][nt] = __builtin_amdgcn_mfma_f32_16x16x32_bf16(
              a[mt], bw[nt], acc[mt][nt], 0, 0, 0);
    }
    __syncthreads();  // all waves done reading xe before hbuf overwrites it
    // epilogue: relu -> swizzled LDS write (no residual at layer 0)
#pragma unroll
    for (int mt = 0; mt < 4; ++mt)
#pragma unroll
      for (int nt = 0; nt < 4; ++nt) {
        int col = wb + nt * 16 + l15;
#pragma unroll
        for (int j = 0; j < 4; ++j) {
          int row = mt * 16 + lq * 4 + j;
          float hv = fmaxf(acc[mt][nt][j], 0.f);
          int byte = (row * H + col) * 2;
          byte ^= ((row & 7) << 4);
          *(bf16*)((char*)hbuf + byte) = __float2bfloat16(hv);
        }
      }
  }
  __syncthreads();

  // ---- hidden residual layers (rolled, B-fragment 1-step prefetch) ----
#pragma unroll 1
  for (int l = 0; l < NLAYERS_HIDDEN; ++l) {
    const bf16* W = wth + (size_t)(e * 3 + l) * WTH_PER_L + lane * 8;
    const float* bias = bh + (e * 3 + l) * H;
    const float sc = scal[e * 3 + l];
#pragma unroll
    for (int nt = 0; nt < 4; ++nt) {
      float b = bias[wb + nt * 16 + l15];
      f32x4 bv = {b, b, b, b};
#pragma unroll
      for (int mt = 0; mt < 4; ++mt) acc[mt][nt] = bv;
    }
    bf16x8 bwc[4];
#pragma unroll
    for (int nt = 0; nt < 4; ++nt)
      bwc[nt] = *(const bf16x8*)(W + (wid * 4 + nt) * CHUNK);
#pragma unroll 1
    for (int kb = 0; kb < 8; ++kb) {
      bf16x8 bwn[4];
      int kn = (kb < 7) ? kb + 1 : kb;  // clamped prefetch
#pragma unroll
      for (int nt = 0; nt < 4; ++nt)
        bwn[nt] = *(const bf16x8*)(W + (kn * 16 + wid * 4 + nt) * CHUNK);
      bf16x8 a[4];
#pragma unroll
      for (int mt = 0; mt < 4; ++mt) {
        int row = mt * 16 + l15;
        int byte = (row * H + kb * 32 + lq * 8) * 2;
        byte ^= ((row & 7) << 4);
        a[mt] = *(const bf16x8*)((const char*)hbuf + byte);
      }
#pragma unroll
      for (int mt = 0; mt < 4; ++mt)
#pragma unroll
        for (int nt = 0; nt < 4; ++nt)
          acc[mt][nt] = __builtin_amdgcn_mfma_f32_16x16x32_bf16(
              a[mt], bwc[nt], acc[mt][nt], 0, 0, 0);
#pragma unroll
      for (int nt = 0; nt < 4; ++nt) bwc[nt] = bwn[nt];
    }
    __syncthreads();  // all waves done READING hbuf before overwrite
#pragma unroll
    for (int mt = 0; mt < 4; ++mt)
#pragma unroll
      for (int nt = 0; nt < 4; ++nt) {
        int col = wb + nt * 16 + l15;
#pragma unroll
        for (int j = 0; j < 4; ++j) {
          int row = mt * 16 + lq * 4 + j;
          int byte = (row * H + col) * 2;
          byte ^= ((row & 7) << 4);
          bf16* p = (bf16*)((char*)hbuf + byte);
          float hp = __bfloat162float(*p);  // residual: same-thread RMW
          float hv = sc * fmaxf(acc[mt][nt][j], 0.f) + hp;
          *p = __float2bfloat16(hv);
        }
      }
    __syncthreads();
  }

  // ---- output layer: h[64xH] @ wtout^T -> fbuf fp32 ----
  {
    const bf16* W = wtout + (size_t)e * WTOUT_PER_E + lane * 8;
    const float* bias = bout + e * DOUT;
    f32x4 facc[4];
#pragma unroll
    for (int nt = 0; nt < 4; ++nt) {
      float b = bias[nt * 16 + l15];
      f32x4 bv = {b, b, b, b};
      facc[nt] = bv;
    }
    const int arow = wid * 16 + l15;  // wave w owns output rows [16w,16w+16)
#pragma unroll 1
    for (int kb = 0; kb < 8; ++kb) {
      int byte = (arow * H + kb * 32 + lq * 8) * 2;
      byte ^= ((arow & 7) << 4);
      bf16x8 a = *(const bf16x8*)((const char*)hbuf + byte);
#pragma unroll
      for (int nt = 0; nt < 4; ++nt) {
        bf16x8 bw = *(const bf16x8*)(W + (kb * 4 + nt) * CHUNK);
        facc[nt] = __builtin_amdgcn_mfma_f32_16x16x32_bf16(a, bw, facc[nt], 0, 0, 0);
      }
    }
    __syncthreads();  // hbuf dead; fbuf overlays it
#pragma unroll
    for (int nt = 0; nt < 4; ++nt) {
      int col = nt * 16 + l15;
#pragma unroll
      for (int j = 0; j < 4; ++j) {
        int row = wid * 16 + lq * 4 + j;
        fbuf[row * FB_STRIDE + col] = facc[nt][j];
      }
    }
  }
  __syncthreads();

  // ---- coalesced scatter: full 256B rows via float4 lanes ----
#pragma unroll 1
  for (int p = 0; p < 4; ++p) {
    int item = p * 256 + tid;
    int row = item >> 4;
    int ch = item & 15;
    int ri = ridx[row];
    if (ri >= 0) {
      f32x4 v = *(const f32x4*)(fbuf + row * FB_STRIDE + ch * 4);
      float inv = indim_s[row];
      v[0] /= inv; v[1] /= inv; v[2] /= inv; v[3] /= inv;
      *(f32x4*)(out + (size_t)ri * DOUT + ch * 4) = v;
    }
  }
}

// ---------------- launch ----------------
extern "C" void kernel_launch(void* const* d_in, const int* in_sizes, int n_in,
                              void* d_out, int out_size, void* d_ws,
                              size_t ws_size, hipStream_t stream) {
  const float* x = (const float*)d_in[0];
  const float* in_dim = (const float*)d_in[1];
  const int* layer_id = (const int*)d_in[2];
  const float* W0 = (const float*)d_in[3];
  const float* b0 = (const float*)d_in[4];
  const float* Wh = (const float*)d_in[5];
  const float* bh = (const float*)d_in[6];
  const float* scal = (const float*)d_in[7];
  const float* Wout = (const float*)d_in[8];
  const float* bout = (const float*)d_in[9];
  float* out = (float*)d_out;

  char* ws = (char*)d_ws;
  int* gcnt = (int*)ws;                                  // 16 B
  int* idx = (int*)(ws + 16);                            // NC*N_ROWS*4 = 1 MB
  bf16* wt0 = (bf16*)(ws + 16 + (size_t)NC * N_ROWS * 4);
  bf16* wth = wt0 + NC * WT0_PER_E;
  bf16* wtout = wth + NC * 3 * WTH_PER_L;

  hipMemsetAsync(gcnt, 0, NC * sizeof(int), stream);
  bucket_kernel<<<N_ROWS / 256, 256, 0, stream>>>(layer_id, gcnt, idx);
  prep_weights<<<512, 256, 0, stream>>>(W0, Wh, Wout, wt0, wth, wtout);
  mlp_kernel<<<dim3(N_ROWS / BM, NC), 256, 0, stream>>>(
      x, in_dim, gcnt, idx, wt0, b0, wth, bh, scal, wtout, bout, out);
}